// Round 2
// baseline (2085.249 us; speedup 1.0000x reference)
//
#include <hip/hip_runtime.h>
#include <float.h>

// Problem constants
#define NBATCH 32
#define NCHAN  256
#define NHW    1024          // 32*32
#define NTOK   32768         // NBATCH * NHW
#define NK     8192          // codebook size
#define ND     256           // token dim
#define ZELEMS 8388608       // NBATCH*NCHAN*NHW
#define OUT_LOSS 8388608
#define OUT_IDX  8388611
#define MARGIN   6e-5f       // candidate margin: 1.5*ulp(256..512) + e2 spread + slack

// ws layout (floats):
//  [0]                      loss sum accumulator
//  [64 .. 64+8192)          en[k] = ||e_k||^2  (fp32, pre-screen only)
//  [64+8192 .. +32768)      idx (int32) per token
//  [41024 .. )              part4: float4 [32768 tokens][32 kblocks]  (16 MB)

// ---------------------------------------------------------------- kernel 1
__global__ __launch_bounds__(256) void k_en(const float* __restrict__ E,
                                            float* __restrict__ en,
                                            float* __restrict__ acc) {
    int t = threadIdx.x;
    int wv = t >> 6, lane = t & 63;
    int k = blockIdx.x * 4 + wv;
    const float4* E4 = (const float4*)E;
    float4 v = E4[k * 64 + lane];
    float s = v.x * v.x + v.y * v.y + v.z * v.z + v.w * v.w;
    #pragma unroll
    for (int off = 32; off > 0; off >>= 1) s += __shfl_down(s, off, 64);
    if (lane == 0) en[k] = s;
    if (blockIdx.x == 0 && t == 0) acc[0] = 0.0f;  // zero loss accumulator
}

// ---------------------------------------------------------------- kernel 2
// fp32 pre-screen: s_k = ||e_k||^2 - 2 z.e_k ; per row keep top-2 per 256-code
// kblock. Grid: (32 kblocks, 256 token blocks), 256 thr. Inner loop: two
// 128-code tiles. Tile: 128 tokens x 128 codes, BK=32, double-buffered LDS.
__global__ __launch_bounds__(256, 2) void k_dist(const float* __restrict__ zg,
                                                 const float* __restrict__ E,
                                                 const float* __restrict__ en,
                                                 float4* __restrict__ part4) {
    __shared__ float zs[2][32][128];
    __shared__ float es[2][32][132];

    const int t   = threadIdx.x;
    const int kbb = blockIdx.x;           // 0..31 (256 codes each)
    const int mb  = blockIdx.y;           // 0..255
    const int n0  = mb * 128;
    const int zbase = (mb >> 3) * (NCHAN * NHW) + ((mb & 7) << 7);
    const int tn = t & 15;                // token group
    const int tk = t >> 4;                // code group

    // running top-2 held by finalizer threads (t<128)
    float fv1 = FLT_MAX, fv2 = FLT_MAX;
    int   fi1 = 0,       fi2 = 0;

    for (int kt = 0; kt < 2; ++kt) {
        const int k0 = kbb * 256 + kt * 128;

        float pz[16], pe[16];
        auto load_regs = [&](int ch) {
            const int c0 = ch * 32;
            #pragma unroll
            for (int r = 0; r < 16; ++r) {
                int idx = t + 256 * r;
                int c = idx >> 7, j = idx & 127;
                pz[r] = zg[zbase + (c0 + c) * NHW + j];
            }
            #pragma unroll
            for (int r = 0; r < 16; ++r) {
                int idx = t + 256 * r;
                int c = idx & 31, k = idx >> 5;
                pe[r] = E[(k0 + k) * ND + c0 + c];
            }
        };
        auto store_lds = [&](int buf) {
            #pragma unroll
            for (int r = 0; r < 16; ++r) {
                int idx = t + 256 * r;
                int c = idx >> 7, j = idx & 127;
                zs[buf][c][j] = pz[r];
            }
            #pragma unroll
            for (int r = 0; r < 16; ++r) {
                int idx = t + 256 * r;
                int c = idx & 31, k = idx >> 5;
                es[buf][c][k] = pe[r];
            }
        };

        float acc[8][8];
        #pragma unroll
        for (int i = 0; i < 8; ++i)
            #pragma unroll
            for (int j = 0; j < 8; ++j) acc[i][j] = 0.0f;

        load_regs(0);
        store_lds(0);
        __syncthreads();

        for (int ch = 0; ch < 8; ++ch) {
            const int buf = ch & 1;
            if (ch < 7) load_regs(ch + 1);
            #pragma unroll 4
            for (int c = 0; c < 32; ++c) {
                float4 za = *(const float4*)&zs[buf][c][4 * tn];
                float4 zb = *(const float4*)&zs[buf][c][64 + 4 * tn];
                float4 ea = *(const float4*)&es[buf][c][4 * tk];
                float4 eb = *(const float4*)&es[buf][c][64 + 4 * tk];
                float zr[8] = {za.x, za.y, za.z, za.w, zb.x, zb.y, zb.z, zb.w};
                float er[8] = {ea.x, ea.y, ea.z, ea.w, eb.x, eb.y, eb.z, eb.w};
                #pragma unroll
                for (int i = 0; i < 8; ++i)
                    #pragma unroll
                    for (int j = 0; j < 8; ++j)
                        acc[i][j] = fmaf(zr[i], er[j], acc[i][j]);
            }
            if (ch < 7) {
                store_lds(buf ^ 1);
                __syncthreads();
            }
        }

        // per-thread top-2 per row over its 8 columns
        float env[8];
        #pragma unroll
        for (int j = 0; j < 8; ++j) {
            int kj = (j < 4) ? (4 * tk + j) : (64 + 4 * tk + j - 4);
            env[j] = en[k0 + kj];
        }
        float bv1[8], bv2[8]; int bi1[8], bi2[8];
        #pragma unroll
        for (int i = 0; i < 8; ++i) { bv1[i] = FLT_MAX; bv2[i] = FLT_MAX; bi1[i] = 0; bi2[i] = 0; }
        #pragma unroll
        for (int j = 0; j < 8; ++j) {
            int kj = (j < 4) ? (4 * tk + j) : (64 + 4 * tk + j - 4);
            #pragma unroll
            for (int i = 0; i < 8; ++i) {
                float s = fmaf(-2.0f, acc[i][j], env[j]);
                if (s < bv1[i]) { bv2[i] = bv1[i]; bi2[i] = bi1[i]; bv1[i] = s; bi1[i] = k0 + kj; }
                else if (s < bv2[i]) { bv2[i] = s; bi2[i] = k0 + kj; }
            }
        }

        // cross-thread: [16 groups][128 rows][2 slots] in buf0 LDS regions
        float* redv = &zs[0][0][0];   // 4096 floats
        int*   redi = (int*)&es[0][0][0];
        #pragma unroll
        for (int i = 0; i < 8; ++i) {
            int row = (i < 4) ? (4 * tn + i) : (64 + 4 * tn + i - 4);
            redv[(tk * 128 + row) * 2 + 0] = bv1[i];
            redv[(tk * 128 + row) * 2 + 1] = bv2[i];
            redi[(tk * 128 + row) * 2 + 0] = bi1[i];
            redi[(tk * 128 + row) * 2 + 1] = bi2[i];
        }
        __syncthreads();
        if (t < 128) {
            #pragma unroll 4
            for (int g = 0; g < 16; ++g) {
                #pragma unroll
                for (int s2 = 0; s2 < 2; ++s2) {
                    float v = redv[(g * 128 + t) * 2 + s2];
                    int  id = redi[(g * 128 + t) * 2 + s2];
                    if (v < fv1) { fv2 = fv1; fi2 = fi1; fv1 = v; fi1 = id; }
                    else if (v < fv2) { fv2 = v; fi2 = id; }
                }
            }
        }
        __syncthreads();   // protect buf0 LDS from next tile's staging
    }

    if (t < 128)
        part4[(size_t)(n0 + t) * 32 + kbb] =
            make_float4(fv1, __int_as_float(fi1), fv2, __int_as_float(fi2));
}

// ---------------------------------------------------------------- kernel 3
// Refine: per row (1 wave), mimic the reference's fp32 rounding:
//   d_q(k) = fl32( z2f - fl32(2 * <z,e_k>_fp64) ),  argmin, first-index ties.
__global__ __launch_bounds__(256) void k_refine(const float* __restrict__ zg,
                                                const float* __restrict__ E,
                                                const float4* __restrict__ part4,
                                                int* __restrict__ idxw,
                                                float* __restrict__ outF) {
    const int w = threadIdx.x >> 6, l = threadIdx.x & 63;
    const int n = blockIdx.x * 4 + w;
    const int b = n >> 10, hw = n & 1023;
    const float* zrow = zg + b * (NCHAN * NHW) + hw;

    float zreg[4];
    #pragma unroll
    for (int j = 0; j < 4; ++j) zreg[j] = zrow[(4 * l + j) * NHW];

    double z2 = 0.0;
    #pragma unroll
    for (int j = 0; j < 4; ++j) z2 += (double)zreg[j] * (double)zreg[j];
    #pragma unroll
    for (int m = 1; m < 64; m <<= 1) z2 += __shfl_xor(z2, m, 64);
    const float z2f = (float)z2;   // correctly-rounded ||z||^2

    float4 c4 = make_float4(FLT_MAX, 0.0f, FLT_MAX, 0.0f);
    if (l < 32) c4 = part4[(size_t)n * 32 + l];
    float vmin = fminf(c4.x, c4.z);
    #pragma unroll
    for (int m = 1; m < 64; m <<= 1) vmin = fminf(vmin, __shfl_xor(vmin, m, 64));
    const float thr = vmin + MARGIN;

    unsigned long long m1 = __ballot(l < 32 && c4.x <= thr);
    unsigned long long m2 = __ballot(l < 32 && c4.z <= thr);

    float bdq = FLT_MAX; int bidx = 0x7fffffff;
    #pragma unroll
    for (int pass = 0; pass < 2; ++pass) {
        unsigned long long mm = pass ? m2 : m1;
        int ibits = pass ? __float_as_int(c4.w) : __float_as_int(c4.y);
        while (mm) {
            int src = __ffsll(mm) - 1; mm &= mm - 1;
            int cidx = __shfl(ibits, src, 64);
            const float4 e4 = *(const float4*)&E[cidx * ND + 4 * l];
            double g = (double)zreg[0] * (double)e4.x + (double)zreg[1] * (double)e4.y
                     + (double)zreg[2] * (double)e4.z + (double)zreg[3] * (double)e4.w;
            #pragma unroll
            for (int mk = 1; mk < 64; mk <<= 1) g += __shfl_xor(g, mk, 64);
            float c  = (float)(2.0 * g);   // fl32(2*g_exact)
            float dq = z2f - c;            // fl32 subtract: HW half-even, binade-aware
            if (dq < bdq || (dq == bdq && cidx < bidx)) { bdq = dq; bidx = cidx; }
        }
    }
    if (l == 0) { idxw[n] = bidx; outF[OUT_IDX + n] = (float)bidx; }
}

// ---------------------------------------------------------------- kernel 4
__global__ __launch_bounds__(256) void k_gather(const float* __restrict__ E,
                                                const float* __restrict__ zg,
                                                const int* __restrict__ idxw,
                                                float* __restrict__ out,
                                                float* __restrict__ acc) {
    int g = blockIdx.x * 256 + threadIdx.x;
    int o4 = g * 4;
    int b  = o4 >> 18;
    int c  = (o4 >> 10) & 255;
    int hw = o4 & 1023;
    int n0 = b * NHW + hw;
    float4 zv = *(const float4*)&zg[o4];
    int i0 = idxw[n0], i1 = idxw[n0 + 1], i2 = idxw[n0 + 2], i3 = idxw[n0 + 3];
    float e0 = E[i0 * ND + c], e1 = E[i1 * ND + c];
    float e2 = E[i2 * ND + c], e3 = E[i3 * ND + c];
    *(float4*)&out[o4] = make_float4(e0, e1, e2, e3);
    float d0 = e0 - zv.x, d1 = e1 - zv.y, d2 = e2 - zv.z, d3 = e3 - zv.w;
    float s = d0 * d0 + d1 * d1 + d2 * d2 + d3 * d3;
    #pragma unroll
    for (int off = 32; off > 0; off >>= 1) s += __shfl_down(s, off, 64);
    __shared__ float wred[4];
    int lane = threadIdx.x & 63, wv = threadIdx.x >> 6;
    if (lane == 0) wred[wv] = s;
    __syncthreads();
    if (threadIdx.x == 0)
        atomicAdd(acc, wred[0] + wred[1] + wred[2] + wred[3]);
}

// ---------------------------------------------------------------- kernel 5
__global__ void k_loss(const float* __restrict__ acc, float* __restrict__ out) {
    if (threadIdx.x == 0) {
        float mse = acc[0] / 8388608.0f;
        out[OUT_LOSS + 0] = 1.25f * mse;
        out[OUT_LOSS + 1] = 0.25f * mse;
        out[OUT_LOSS + 2] = mse;
    }
}

extern "C" void kernel_launch(void* const* d_in, const int* in_sizes, int n_in,
                              void* d_out, int out_size, void* d_ws, size_t ws_size,
                              hipStream_t stream) {
    const float* zg = (const float*)d_in[0];
    const float* E  = (const float*)d_in[1];
    float* out = (float*)d_out;
    float* wsf = (float*)d_ws;
    float*  acc   = wsf;
    float*  en    = wsf + 64;
    int*    idxw  = (int*)(wsf + 64 + NK);
    float4* part4 = (float4*)(wsf + 64 + NK + NTOK);   // 16 MB

    k_en    <<<NK / 4, 256, 0, stream>>>(E, en, acc);
    k_dist  <<<dim3(32, 256), 256, 0, stream>>>(zg, E, en, part4);
    k_refine<<<NTOK / 4, 256, 0, stream>>>(zg, E, part4, idxw, out);
    k_gather<<<ZELEMS / 1024, 256, 0, stream>>>(E, zg, idxw, out, acc);
    k_loss  <<<1, 64, 0, stream>>>(acc, out);
}

// Round 3
// 415.508 us; speedup vs baseline: 5.0186x; 5.0186x over previous
//
#include <hip/hip_runtime.h>
#include <float.h>

// Problem constants
#define NBATCH 32
#define NCHAN  256
#define NHW    1024          // 32*32
#define NTOK   32768         // NBATCH * NHW
#define NK     8192          // codebook size
#define ND     256           // token dim
#define ZELEMS 8388608       // NBATCH*NCHAN*NHW
#define OUT_LOSS 8388608
#define OUT_IDX  8388611
#define MARGIN   1.2e-4f     // bf16 pre-screen err (6sig~2e-5) + quant tie window (3.05e-5) + slack

typedef short bf16x8 __attribute__((ext_vector_type(8)));
typedef float f32x4  __attribute__((ext_vector_type(4)));

__device__ __forceinline__ void gl_lds16(const void* g, void* l) {
    __builtin_amdgcn_global_load_lds(
        (const __attribute__((address_space(1))) unsigned int*)g,
        (__attribute__((address_space(3))) unsigned int*)l, 16, 0, 0);
}

__device__ __forceinline__ unsigned short f2bf(float f) {   // RNE
    unsigned int u = __float_as_uint(f);
    u += 0x7FFFu + ((u >> 16) & 1u);
    return (unsigned short)(u >> 16);
}

// ws layout (floats):
//  [0]          loss accumulator
//  [64..64+8192)   en[k] = ||e_k||^2 (fp32 pre-screen)
//  [8256..+32768)  idxw (int)
//  [41024..)       part2: float2 [32768 tok][32 slots]  (8 MB)
//  then            Epre: bf16-swizzled E, [64 tile][8 kc][128 n][32 k] (4 MB)
// Zpre (bf16-swizzled z, 16 MB) lives in d_out[0..16MB) until k_gather rewrites it.

// ---------------------------------------------------------------- kernel 1
__global__ __launch_bounds__(256) void k_en(const float* __restrict__ E,
                                            float* __restrict__ en,
                                            float* __restrict__ acc) {
    int t = threadIdx.x;
    int wv = t >> 6, lane = t & 63;
    int k = blockIdx.x * 4 + wv;
    const float4* E4 = (const float4*)E;
    float4 v = E4[k * 64 + lane];
    float s = v.x * v.x + v.y * v.y + v.z * v.z + v.w * v.w;
    #pragma unroll
    for (int off = 32; off > 0; off >>= 1) s += __shfl_down(s, off, 64);
    if (lane == 0) en[k] = s;
    if (blockIdx.x == 0 && t == 0) acc[0] = 0.0f;
}

// ---------------------------------------------------------------- cast E
// Epre[tile=code>>7][kc=c>>5][code&127][c&31], contiguous 8KB per (tile,kc)
__global__ __launch_bounds__(256) void k_castE(const float* __restrict__ E,
                                               unsigned short* __restrict__ Epre) {
    int g = blockIdx.x * 256 + threadIdx.x;      // 8192*64
    int code = g >> 6, c0 = (g & 63) * 4;
    float4 v = *(const float4*)&E[code * ND + c0];
    unsigned short* p = Epre + (((code >> 7) * 8 + (c0 >> 5)) * 4096
                                + (code & 127) * 32 + (c0 & 31));
    p[0] = f2bf(v.x); p[1] = f2bf(v.y); p[2] = f2bf(v.z); p[3] = f2bf(v.w);
}

// ---------------------------------------------------------------- cast Z
// Zpre[tile=token>>7][kc=c>>5][token&127][c&31]; LDS transpose for coalescing
__global__ __launch_bounds__(256) void k_castZ(const float* __restrict__ zg,
                                               unsigned short* __restrict__ Zpre) {
    __shared__ unsigned short buf[128][34];
    int bi = blockIdx.x;                  // 32 b * 8 kc * 8 hwt
    int b = bi >> 6, kc = (bi >> 3) & 7, hwt = bi & 7;
    int c0 = kc * 32, hw0 = hwt * 128;
    int t = threadIdx.x;
    #pragma unroll
    for (int r = 0; r < 4; ++r) {
        int idx = r * 256 + t;
        int c = idx >> 5, q = idx & 31;
        float4 v = *(const float4*)&zg[(b * 256 + c0 + c) * 1024 + hw0 + q * 4];
        buf[q * 4 + 0][c] = f2bf(v.x);
        buf[q * 4 + 1][c] = f2bf(v.y);
        buf[q * 4 + 2][c] = f2bf(v.z);
        buf[q * 4 + 3][c] = f2bf(v.w);
    }
    __syncthreads();
    int hw = t >> 1, half = t & 1;
    unsigned int u[8];
    #pragma unroll
    for (int k = 0; k < 8; ++k)
        u[k] = (unsigned int)buf[hw][half * 16 + 2 * k]
             | ((unsigned int)buf[hw][half * 16 + 2 * k + 1] << 16);
    char* outp = (char*)Zpre + ((size_t)((b * 8 + hwt) * 8 + kc) * 8192)
               + hw * 64 + half * 32;
    ((uint4*)outp)[0] = make_uint4(u[0], u[1], u[2], u[3]);
    ((uint4*)outp)[1] = make_uint4(u[4], u[5], u[6], u[7]);
}

// ---------------------------------------------------------------- kernel 2
// MFMA distance pre-screen, S^T orientation: D[code][token].
// Block: 256 codes (2 passes of 128) x 128 tokens. Grid (32 kbb, 256 mb).
// Per (token, 256-code slot): top-2 of s = ||e||^2 - 2 z.e, with the 8-bit
// local code index embedded in the low mantissa bits of s (quant 2.4e-7).
__global__ __launch_bounds__(256, 3) void k_dist(const unsigned short* __restrict__ Epre,
                                                 const unsigned short* __restrict__ Zpre,
                                                 const float* __restrict__ en,
                                                 float2* __restrict__ part2) {
    __shared__ unsigned short E_s[128][32];   // [code][k] bf16, 8 KB
    __shared__ unsigned short Z_s[128][32];   // [token][k] bf16, 8 KB
    __shared__ float en_s[256];
    __shared__ float2 red[2][128];

    const int t   = threadIdx.x;
    const int kbb = blockIdx.x;               // 0..31
    const int mb  = blockIdx.y;               // 0..255
    const int n0  = mb * 128;
    const int w    = t >> 6, lane = t & 63;
    const int quad = lane >> 4, c0 = lane & 15;
    const int wm = w >> 1, wn = w & 1;        // wm: code-half, wn: token-half

    en_s[t] = en[kbb * 256 + t];

    // staging split: waves 0,1 -> E_s ; waves 2,3 -> Z_s (4 KB each)
    const char* srcZ = (const char*)Zpre + (size_t)(mb * 8) * 8192
                     + (w - 2) * 4096 + lane * 16;
    char* dst = (w < 2) ? ((char*)&E_s[0][0] + w * 4096)
                        : ((char*)&Z_s[0][0] + (w - 2) * 4096);

    float fv1 = FLT_MAX, fv2 = FLT_MAX;       // running top-2 (threads t<128)

    for (int kt = 0; kt < 2; ++kt) {
        const char* srcE = (const char*)Epre + (size_t)((kbb * 2 + kt) * 8) * 8192
                         + w * 4096 + lane * 16;
        f32x4 acc[4][4];
        #pragma unroll
        for (int i = 0; i < 4; ++i)
            #pragma unroll
            for (int j = 0; j < 4; ++j) acc[i][j] = (f32x4)0.0f;

        for (int kc = 0; kc < 8; ++kc) {
            __syncthreads();   // LDS free (prev readers done)
            const char* src = (w < 2) ? (srcE + kc * 8192) : (srcZ + kc * 8192);
            #pragma unroll
            for (int r = 0; r < 4; ++r)
                gl_lds16(src + r * 1024, dst + r * 1024);
            __syncthreads();   // drains vmcnt before barrier

            bf16x8 ea[4], zb[4];
            #pragma unroll
            for (int i = 0; i < 4; ++i)
                ea[i] = *(const bf16x8*)&E_s[wm * 64 + i * 16 + c0][quad * 8];
            #pragma unroll
            for (int j = 0; j < 4; ++j)
                zb[j] = *(const bf16x8*)&Z_s[wn * 64 + j * 16 + c0][quad * 8];
            #pragma unroll
            for (int i = 0; i < 4; ++i)
                #pragma unroll
                for (int j = 0; j < 4; ++j)
                    acc[i][j] = __builtin_amdgcn_mfma_f32_16x16x32_bf16(
                        ea[i], zb[j], acc[i][j], 0, 0, 0);
        }

        // ---- epilogue for this 128-code pass ----
        f32x4 env[4];
        #pragma unroll
        for (int i = 0; i < 4; ++i)
            env[i] = *(f32x4*)&en_s[kt * 128 + wm * 64 + i * 16 + quad * 4];

        float v1[4], v2[4];
        #pragma unroll
        for (int j = 0; j < 4; ++j) { v1[j] = FLT_MAX; v2[j] = FLT_MAX; }

        #pragma unroll
        for (int i = 0; i < 4; ++i)
            #pragma unroll
            for (int r = 0; r < 4; ++r) {
                float en0 = env[i][r];
                int ecode = (kt << 7) | (wm << 6) | (i << 4) | (quad << 2) | r;
                #pragma unroll
                for (int j = 0; j < 4; ++j) {
                    float s  = fmaf(-2.0f, acc[i][j][r], en0);
                    float se = __int_as_float((__float_as_int(s) & 0xFFFFFF00) | ecode);
                    float nv1 = fminf(v1[j], se);
                    v2[j] = __builtin_amdgcn_fmed3f(se, v1[j], v2[j]);
                    v1[j] = nv1;
                }
            }
        // quad butterfly (codes spread over quads): xor 16, 32
        #pragma unroll
        for (int m = 16; m <= 32; m <<= 1)
            #pragma unroll
            for (int j = 0; j < 4; ++j) {
                float b1 = __shfl_xor(v1[j], m, 64);
                float b2 = __shfl_xor(v2[j], m, 64);
                float hi = fmaxf(v1[j], b1);
                v1[j] = fminf(v1[j], b1);
                v2[j] = fminf(fminf(hi, v2[j]), b2);
            }
        if (quad == 0) {
            #pragma unroll
            for (int j = 0; j < 4; ++j)
                red[wm][wn * 64 + j * 16 + c0] = make_float2(v1[j], v2[j]);
        }
        __syncthreads();
        if (t < 128) {
            float2 A0 = red[0][t], B0 = red[1][t];
            float hi = fmaxf(A0.x, B0.x);
            float m1 = fminf(A0.x, B0.x);
            float m2 = fminf(fminf(hi, A0.y), B0.y);
            float hh = fmaxf(fv1, m1);
            fv1 = fminf(fv1, m1);
            fv2 = fminf(fminf(hh, fv2), m2);
        }
    }
    if (t < 128)
        part2[(size_t)(n0 + t) * 32 + kbb] = make_float2(fv1, fv2);
}

// ---------------------------------------------------------------- kernel 3
// Refine: per row (1 wave), mimic reference fp32 rounding:
//   d_q(k) = fl32( z2f - fl32(2*<z,e_k>_fp64) ), argmin, first-index ties.
__global__ __launch_bounds__(256) void k_refine(const float* __restrict__ zg,
                                                const float* __restrict__ E,
                                                const float2* __restrict__ part2,
                                                int* __restrict__ idxw,
                                                float* __restrict__ outF) {
    const int w = threadIdx.x >> 6, l = threadIdx.x & 63;
    const int n = blockIdx.x * 4 + w;
    const int b = n >> 10, hw = n & 1023;
    const float* zrow = zg + b * (NCHAN * NHW) + hw;

    float zreg[4];
    #pragma unroll
    for (int j = 0; j < 4; ++j) zreg[j] = zrow[(4 * l + j) * NHW];

    double z2 = 0.0;
    #pragma unroll
    for (int j = 0; j < 4; ++j) z2 += (double)zreg[j] * (double)zreg[j];
    #pragma unroll
    for (int m = 1; m < 64; m <<= 1) z2 += __shfl_xor(z2, m, 64);
    const float z2f = (float)z2;

    float2 p = make_float2(FLT_MAX, FLT_MAX);
    if (l < 32) p = part2[(size_t)n * 32 + l];
    int code1 = (l << 8) | (__float_as_int(p.x) & 0xFF);
    int code2 = (l << 8) | (__float_as_int(p.y) & 0xFF);

    float vmin = p.x;
    #pragma unroll
    for (int m = 1; m < 64; m <<= 1) vmin = fminf(vmin, __shfl_xor(vmin, m, 64));
    const float thr = vmin + MARGIN;

    unsigned long long m1 = __ballot(l < 32 && p.x <= thr);
    unsigned long long m2 = __ballot(l < 32 && p.y <= thr);

    float bdq = FLT_MAX; int bidx = 0x7fffffff;
    #pragma unroll
    for (int pass = 0; pass < 2; ++pass) {
        unsigned long long mm = pass ? m2 : m1;
        int ibits = pass ? code2 : code1;
        while (mm) {
            int src = __ffsll(mm) - 1; mm &= mm - 1;
            int cidx = __shfl(ibits, src, 64);
            const float4 e4 = *(const float4*)&E[cidx * ND + 4 * l];
            double g = (double)zreg[0] * (double)e4.x + (double)zreg[1] * (double)e4.y
                     + (double)zreg[2] * (double)e4.z + (double)zreg[3] * (double)e4.w;
            #pragma unroll
            for (int mk = 1; mk < 64; mk <<= 1) g += __shfl_xor(g, mk, 64);
            float c  = (float)(2.0 * g);
            float dq = z2f - c;
            if (dq < bdq || (dq == bdq && cidx < bidx)) { bdq = dq; bidx = cidx; }
        }
    }
    if (l == 0) { idxw[n] = bidx; outF[OUT_IDX + n] = (float)bidx; }
}

// ---------------------------------------------------------------- kernel 4
__global__ __launch_bounds__(256) void k_gather(const float* __restrict__ E,
                                                const float* __restrict__ zg,
                                                const int* __restrict__ idxw,
                                                float* __restrict__ out,
                                                float* __restrict__ acc) {
    int g = blockIdx.x * 256 + threadIdx.x;
    int o4 = g * 4;
    int b  = o4 >> 18;
    int c  = (o4 >> 10) & 255;
    int hw = o4 & 1023;
    int n0 = b * NHW + hw;
    float4 zv = *(const float4*)&zg[o4];
    int i0 = idxw[n0], i1 = idxw[n0 + 1], i2 = idxw[n0 + 2], i3 = idxw[n0 + 3];
    float e0 = E[i0 * ND + c], e1 = E[i1 * ND + c];
    float e2 = E[i2 * ND + c], e3 = E[i3 * ND + c];
    *(float4*)&out[o4] = make_float4(e0, e1, e2, e3);
    float d0 = e0 - zv.x, d1 = e1 - zv.y, d2 = e2 - zv.z, d3 = e3 - zv.w;
    float s = d0 * d0 + d1 * d1 + d2 * d2 + d3 * d3;
    #pragma unroll
    for (int off = 32; off > 0; off >>= 1) s += __shfl_down(s, off, 64);
    __shared__ float wred[4];
    int lane = threadIdx.x & 63, wv = threadIdx.x >> 6;
    if (lane == 0) wred[wv] = s;
    __syncthreads();
    if (threadIdx.x == 0)
        atomicAdd(acc, wred[0] + wred[1] + wred[2] + wred[3]);
}

// ---------------------------------------------------------------- kernel 5
__global__ void k_loss(const float* __restrict__ acc, float* __restrict__ out) {
    if (threadIdx.x == 0) {
        float mse = acc[0] / 8388608.0f;
        out[OUT_LOSS + 0] = 1.25f * mse;
        out[OUT_LOSS + 1] = 0.25f * mse;
        out[OUT_LOSS + 2] = mse;
    }
}

extern "C" void kernel_launch(void* const* d_in, const int* in_sizes, int n_in,
                              void* d_out, int out_size, void* d_ws, size_t ws_size,
                              hipStream_t stream) {
    const float* zg = (const float*)d_in[0];
    const float* E  = (const float*)d_in[1];
    float* out = (float*)d_out;
    float* wsf = (float*)d_ws;
    float*  acc   = wsf;
    float*  en    = wsf + 64;
    int*    idxw  = (int*)(wsf + 64 + NK);
    float2* part2 = (float2*)(wsf + 41024);                      // 8 MB
    unsigned short* Epre = (unsigned short*)(wsf + 41024 + 2097152);  // 4 MB
    // Zpre scratch lives in d_out (dead until k_gather rewrites it; refine's
    // index region at float offset 8388611 is beyond the 16 MB Zpre span)
    unsigned short* Zpre = (unsigned short*)d_out;

    k_en    <<<NK / 4, 256, 0, stream>>>(E, en, acc);
    k_castE <<<NK * 64 / 256, 256, 0, stream>>>(E, Epre);
    k_castZ <<<2048, 256, 0, stream>>>(zg, Zpre);
    k_dist  <<<dim3(32, 256), 256, 0, stream>>>(Epre, Zpre, en, part2);
    k_refine<<<NTOK / 4, 256, 0, stream>>>(zg, E, part2, idxw, out);
    k_gather<<<ZELEMS / 1024, 256, 0, stream>>>(E, zg, idxw, out, acc);
    k_loss  <<<1, 64, 0, stream>>>(acc, out);
}

// Round 5
// 348.021 us; speedup vs baseline: 5.9917x; 1.1939x over previous
//
#include <hip/hip_runtime.h>
#include <float.h>

// Problem constants
#define NBATCH 32
#define NCHAN  256
#define NHW    1024          // 32*32
#define NTOK   32768         // NBATCH * NHW
#define NK     8192          // codebook size
#define ND     256           // token dim
#define ZELEMS 8388608       // NBATCH*NCHAN*NHW
#define OUT_LOSS 8388608
#define OUT_IDX  8388611
#define MARGIN   1.2e-4f     // bf16 pre-screen err + fp32 quant tie window + slack

typedef short bf16x8  __attribute__((ext_vector_type(8)));
typedef float f32x4   __attribute__((ext_vector_type(4)));
typedef float f32x16  __attribute__((ext_vector_type(16)));

__device__ __forceinline__ void gl_lds16(const void* g, void* l) {
    __builtin_amdgcn_global_load_lds(
        (const __attribute__((address_space(1))) unsigned int*)g,
        (__attribute__((address_space(3))) unsigned int*)l, 16, 0, 0);
}

__device__ __forceinline__ unsigned short f2bf(float f) {   // RNE
    unsigned int u = __float_as_uint(f);
    u += 0x7FFFu + ((u >> 16) & 1u);
    return (unsigned short)(u >> 16);
}

__device__ __forceinline__ float embed8(float x, int code) {
    return __int_as_float((__float_as_int(x) & 0xFFFFFF00) | code);
}

// ws layout (floats):
//  [0] loss accumulator, [1] block counter (int)
//  [64 .. 64+8192)        en[k] = ||e_k||^2
//  [8256 .. +32768)       idxw (int) per token
//  [41024 .. +2097152)    part2: float2 [32768 tok][32 slots] (8 MB)
//  then                   Epre: bf16-swizzled E [64 tile][8 kc][128 row][64B] (4 MB)
// Zpre (bf16-swizzled z, 16 MB) lives in d_out[0..16MB) until k_gather rewrites it.
// Swizzle: within each 64B row, logical 16B chunk q stored at (q + (row>>1)) & 3.

// ---------------------------------------------------------------- kernel 1
__global__ __launch_bounds__(256) void k_en(const float* __restrict__ E,
                                            float* __restrict__ en,
                                            float* __restrict__ acc,
                                            int* __restrict__ counter) {
    int t = threadIdx.x;
    int wv = t >> 6, lane = t & 63;
    int k = blockIdx.x * 4 + wv;
    const float4* E4 = (const float4*)E;
    float4 v = E4[k * 64 + lane];
    float s = v.x * v.x + v.y * v.y + v.z * v.z + v.w * v.w;
    #pragma unroll
    for (int off = 32; off > 0; off >>= 1) s += __shfl_down(s, off, 64);
    if (lane == 0) en[k] = s;
    if (blockIdx.x == 0 && t == 0) { acc[0] = 0.0f; counter[0] = 0; }
}

// ---------------------------------------------------------------- cast E
__global__ __launch_bounds__(256) void k_castE(const float* __restrict__ E,
                                               unsigned short* __restrict__ Epre) {
    int g = blockIdx.x * 256 + threadIdx.x;      // 8192 codes * 32 chunks
    int code = g >> 5, c16 = g & 31;             // c16: 16B chunk (8 channels)
    int kc = c16 >> 2, qlog = c16 & 3;
    int row = code & 127, tile = code >> 7;
    const float4* E4 = (const float4*)(E + code * ND + c16 * 8);
    float4 a = E4[0], b = E4[1];
    unsigned int u[4];
    u[0] = (unsigned int)f2bf(a.x) | ((unsigned int)f2bf(a.y) << 16);
    u[1] = (unsigned int)f2bf(a.z) | ((unsigned int)f2bf(a.w) << 16);
    u[2] = (unsigned int)f2bf(b.x) | ((unsigned int)f2bf(b.y) << 16);
    u[3] = (unsigned int)f2bf(b.z) | ((unsigned int)f2bf(b.w) << 16);
    int p = (qlog + (row >> 1)) & 3;
    *(uint4*)((char*)Epre + (size_t)(tile * 8 + kc) * 8192 + row * 64 + p * 16) =
        make_uint4(u[0], u[1], u[2], u[3]);
}

// ---------------------------------------------------------------- cast Z
__global__ __launch_bounds__(256) void k_castZ(const float* __restrict__ zg,
                                               unsigned short* __restrict__ Zpre) {
    __shared__ unsigned short buf[128][34];
    int bi = blockIdx.x;                  // 32 b * 8 kc * 8 hwt
    int b = bi >> 6, kc = (bi >> 3) & 7, hwt = bi & 7;
    int c0 = kc * 32, hw0 = hwt * 128;
    int t = threadIdx.x;
    #pragma unroll
    for (int r = 0; r < 4; ++r) {
        int idx = r * 256 + t;
        int c = idx >> 5, q = idx & 31;
        float4 v = *(const float4*)&zg[(b * 256 + c0 + c) * 1024 + hw0 + q * 4];
        buf[q * 4 + 0][c] = f2bf(v.x);
        buf[q * 4 + 1][c] = f2bf(v.y);
        buf[q * 4 + 2][c] = f2bf(v.z);
        buf[q * 4 + 3][c] = f2bf(v.w);
    }
    __syncthreads();
    int row = t >> 1, half = t & 1;
    char* base = (char*)Zpre + (size_t)((b * 8 + hwt) * 8 + kc) * 8192 + row * 64;
    #pragma unroll
    for (int s = 0; s < 2; ++s) {
        int qlog = half * 2 + s;
        unsigned int u[4];
        #pragma unroll
        for (int k = 0; k < 4; ++k) {
            int cc = qlog * 8 + 2 * k;
            u[k] = (unsigned int)buf[row][cc] | ((unsigned int)buf[row][cc + 1] << 16);
        }
        int p = (qlog + (row >> 1)) & 3;
        *(uint4*)(base + p * 16) = make_uint4(u[0], u[1], u[2], u[3]);
    }
}

// ---------------------------------------------------------------- kernel 2
// MFMA pre-screen, D[code][token], 32x32x16 bf16. Block: 256 codes x 128
// tokens, kt-inner (Z staged once per kc), single-barrier double-buffer.
// Per (token, 256-code slot): top-2 smallest s = ||e||^2 - 2 z.e, with the
// 8-bit local code index embedded in the low mantissa bits of s.
__global__ __launch_bounds__(256, 2) void k_dist(const unsigned short* __restrict__ Epre,
                                                 const unsigned short* __restrict__ Zpre,
                                                 const float* __restrict__ en,
                                                 float2* __restrict__ part2) {
    __shared__ __align__(16) char smem[2 * 24576];
    __shared__ float2 red[2][128];
    __shared__ float en_s[256];

    const int t    = threadIdx.x;
    const int kbb  = blockIdx.x;               // 0..31
    const int mb   = blockIdx.y;               // 0..255
    const int n0   = mb * 128;
    const int w    = t >> 6, lane = t & 63;
    const int l31  = lane & 31, lhi = lane >> 5;
    const int wm   = w >> 1, wn = w & 1;
    const int cA   = (lhi + (l31 >> 1)) & 3;   // swizzle base for ks=0

    en_s[t] = en[kbb * 256 + t];

    const char* Ebase = (const char*)Epre + (size_t)(kbb * 2) * 65536;
    const char* Zbase = (const char*)Zpre + (size_t)mb * 65536;

    auto stage = [&](int kc, int buf) {
        char* db = smem + buf * 24576;
        #pragma unroll
        for (int r = 0; r < 6; ++r) {
            int s = w * 6 + r;                 // wave-uniform
            const char* src;
            if (s < 8)       src = Ebase + kc * 8192 + s * 1024;
            else if (s < 16) src = Ebase + 65536 + kc * 8192 + (s - 8) * 1024;
            else             src = Zbase + kc * 8192 + (s - 16) * 1024;
            gl_lds16(src + lane * 16, db + s * 1024 + lane * 16);
        }
    };

    f32x16 acc[2][2][2];                       // [kt][i2][j2]
    #pragma unroll
    for (int kt = 0; kt < 2; ++kt)
        #pragma unroll
        for (int i = 0; i < 2; ++i)
            #pragma unroll
            for (int j = 0; j < 2; ++j) acc[kt][i][j] = (f32x16)0.0f;

    const int rowEoff = (wm * 64 + l31) * 64;
    const int rowZoff = 16384 + (wn * 64 + l31) * 64;
    const int colk[2] = { (cA & 3) * 16, (cA ^ 2) * 16 };

    stage(0, 0);
    for (int kc = 0; kc < 8; ++kc) {
        __syncthreads();                       // drains this chunk's loads
        if (kc < 7) stage(kc + 1, (kc + 1) & 1);
        char* db = smem + (kc & 1) * 24576;

        bf16x8 ea[2][2][2], zb[2][2];          // [kt][i2][ks], [j2][ks]
        #pragma unroll
        for (int ks = 0; ks < 2; ++ks) {
            #pragma unroll
            for (int kt = 0; kt < 2; ++kt)
                #pragma unroll
                for (int i = 0; i < 2; ++i)
                    ea[kt][i][ks] = *(const bf16x8*)(db + kt * 8192 + rowEoff
                                                     + i * 2048 + colk[ks]);
            #pragma unroll
            for (int j = 0; j < 2; ++j)
                zb[j][ks] = *(const bf16x8*)(db + rowZoff + j * 2048 + colk[ks]);
        }
        #pragma unroll
        for (int kt = 0; kt < 2; ++kt)
            #pragma unroll
            for (int ks = 0; ks < 2; ++ks)
                #pragma unroll
                for (int i = 0; i < 2; ++i)
                    #pragma unroll
                    for (int j = 0; j < 2; ++j)
                        acc[kt][i][j] = __builtin_amdgcn_mfma_f32_32x32x16_bf16(
                            ea[kt][i][ks], zb[j][ks], acc[kt][i][j], 0, 0, 0);
    }

    // ---- epilogue: per-token top-2 smallest s = en - 2*dot, index-embedded ----
    float v1[2] = { FLT_MAX, FLT_MAX }, v2[2] = { FLT_MAX, FLT_MAX };
    #pragma unroll
    for (int kt = 0; kt < 2; ++kt)
        #pragma unroll
        for (int i = 0; i < 2; ++i) {
            const int cb = (kt << 7) | (wm << 6) | (i << 5) | (lhi << 2);
            #pragma unroll
            for (int rq = 0; rq < 4; ++rq) {
                f32x4 ev = *(const f32x4*)&en_s[cb + 8 * rq];
                #pragma unroll
                for (int rr = 0; rr < 4; ++rr) {
                    const int r = rq * 4 + rr;
                    const int code = cb + 8 * rq + rr;
                    #pragma unroll
                    for (int j = 0; j < 2; ++j) {
                        float s  = fmaf(-2.0f, acc[kt][i][j][r], ev[rr]);
                        float se = embed8(s, code);
                        v2[j] = __builtin_amdgcn_fmed3f(se, v1[j], v2[j]);
                        v1[j] = fminf(v1[j], se);
                    }
                }
            }
        }
    #pragma unroll
    for (int j = 0; j < 2; ++j) {              // merge lane pairs (xor 32)
        float b1 = __shfl_xor(v1[j], 32, 64);
        float b2 = __shfl_xor(v2[j], 32, 64);
        float hi = fmaxf(v1[j], b1);
        v1[j] = fminf(v1[j], b1);
        v2[j] = fminf(fminf(hi, v2[j]), b2);
    }
    if (lane < 32) {
        #pragma unroll
        for (int j = 0; j < 2; ++j)
            red[wm][wn * 64 + j * 32 + lane] = make_float2(v1[j], v2[j]);
    }
    __syncthreads();
    if (t < 128) {
        float2 A = red[0][t], B = red[1][t];
        float g1 = fminf(A.x, B.x);
        float g2 = fminf(fminf(fmaxf(A.x, B.x), A.y), B.y);
        part2[(size_t)(n0 + t) * 32 + kbb] = make_float2(g1, g2);
    }
}

// ---------------------------------------------------------------- kernel 3
// Refine: per row (1 wave), mimic reference fp32 rounding:
//   d_q(k) = fl32( z2f - fl32(2*<z,e_k>_fp64) ), argmin, first-index ties.
__global__ __launch_bounds__(256) void k_refine(const float* __restrict__ zg,
                                                const float* __restrict__ E,
                                                const float2* __restrict__ part2,
                                                int* __restrict__ idxw,
                                                float* __restrict__ outF) {
    const int w = threadIdx.x >> 6, l = threadIdx.x & 63;
    const int n = blockIdx.x * 4 + w;
    const int b = n >> 10, hw = n & 1023;
    const float* zrow = zg + b * (NCHAN * NHW) + hw;

    float zreg[4];
    #pragma unroll
    for (int j = 0; j < 4; ++j) zreg[j] = zrow[(4 * l + j) * NHW];

    double z2 = 0.0;
    #pragma unroll
    for (int j = 0; j < 4; ++j) z2 += (double)zreg[j] * (double)zreg[j];
    #pragma unroll
    for (int m = 1; m < 64; m <<= 1) z2 += __shfl_xor(z2, m, 64);
    const float z2f = (float)z2;

    float2 p = make_float2(FLT_MAX, FLT_MAX);
    if (l < 32) p = part2[(size_t)n * 32 + l];
    int code1 = (l << 8) | (__float_as_int(p.x) & 0xFF);
    int code2 = (l << 8) | (__float_as_int(p.y) & 0xFF);

    float vmin = p.x;
    #pragma unroll
    for (int m = 1; m < 64; m <<= 1) vmin = fminf(vmin, __shfl_xor(vmin, m, 64));
    const float thr = vmin + MARGIN;

    unsigned long long m1 = __ballot(l < 32 && p.x <= thr);
    unsigned long long m2 = __ballot(l < 32 && p.y <= thr);

    float bdq = FLT_MAX; int bidx = 0x7fffffff;
    #pragma unroll
    for (int pass = 0; pass < 2; ++pass) {
        unsigned long long mm = pass ? m2 : m1;
        int ibits = pass ? code2 : code1;
        while (mm) {
            int src = __ffsll(mm) - 1; mm &= mm - 1;
            int cidx = __shfl(ibits, src, 64);
            const float4 e4 = *(const float4*)&E[cidx * ND + 4 * l];
            double g = (double)zreg[0] * (double)e4.x + (double)zreg[1] * (double)e4.y
                     + (double)zreg[2] * (double)e4.z + (double)zreg[3] * (double)e4.w;
            #pragma unroll
            for (int mk = 1; mk < 64; mk <<= 1) g += __shfl_xor(g, mk, 64);
            float c  = (float)(2.0 * g);
            float dq = z2f - c;
            if (dq < bdq || (dq == bdq && cidx < bidx)) { bdq = dq; bidx = cidx; }
        }
    }
    if (l == 0) { idxw[n] = bidx; outF[OUT_IDX + n] = (float)bidx; }
}

// ---------------------------------------------------------------- kernel 4
// Gather via LDS-staged E rows (coalesced 1KB row loads, XOR-swizzled),
// fused loss accumulation + last-block loss finalization.
__global__ __launch_bounds__(256) void k_gather(const float* __restrict__ E,
                                                const float* __restrict__ zg,
                                                const int* __restrict__ idxw,
                                                float* __restrict__ out,
                                                float* __restrict__ acc,
                                                int* __restrict__ counter) {
    __shared__ __align__(16) float Es[64 * 256];   // 64 rows x 1KB
    __shared__ int sidx[64];
    __shared__ float wred[4];
    const int t = threadIdx.x;
    const int b = blockIdx.x >> 4, ht = blockIdx.x & 15;

    if (t < 64) sidx[t] = idxw[b * 1024 + ht * 64 + t];
    __syncthreads();
    const float4* E4 = (const float4*)E;
    #pragma unroll
    for (int r = 0; r < 16; ++r) {
        int li = r * 256 + t;
        int row = li >> 6, slot = li & 63;         // row 0..63, slot 0..63
        float4 v = E4[(size_t)sidx[row] * 64 + slot];
        *(float4*)&Es[row * 256 + ((slot ^ (row & 15)) * 4)] = v;
    }
    __syncthreads();

    const int hw = t & 63, wv = t >> 6;
    float s = 0.0f;
    #pragma unroll 8
    for (int cc = 0; cc < 64; ++cc) {
        int c = wv * 64 + cc;
        float e = Es[hw * 256 + (((c >> 2) ^ (hw & 15)) * 4) + (c & 3)];
        size_t gi = (size_t)(b * 256 + c) * 1024 + ht * 64 + hw;
        float zv = zg[gi];
        out[gi] = e;
        float d = e - zv;
        s = fmaf(d, d, s);
    }
    #pragma unroll
    for (int off = 32; off > 0; off >>= 1) s += __shfl_down(s, off, 64);
    if ((t & 63) == 0) wred[wv] = s;
    __syncthreads();
    if (t == 0) {
        atomicAdd(acc, wred[0] + wred[1] + wred[2] + wred[3]);
        __threadfence();
        int old = atomicAdd(counter, 1);
        if (old == 511) {
            float total = atomicAdd(acc, 0.0f);   // RMW => device-coherent read
            float mse = total / 8388608.0f;
            out[OUT_LOSS + 0] = 1.25f * mse;
            out[OUT_LOSS + 1] = 0.25f * mse;
            out[OUT_LOSS + 2] = mse;
        }
    }
}

extern "C" void kernel_launch(void* const* d_in, const int* in_sizes, int n_in,
                              void* d_out, int out_size, void* d_ws, size_t ws_size,
                              hipStream_t stream) {
    const float* zg = (const float*)d_in[0];
    const float* E  = (const float*)d_in[1];
    float* out = (float*)d_out;
    float* wsf = (float*)d_ws;
    float*  acc     = wsf;
    int*    counter = (int*)(wsf + 1);
    float*  en      = wsf + 64;
    int*    idxw    = (int*)(wsf + 64 + NK);
    float2* part2   = (float2*)(wsf + 64 + NK + NTOK);            // 8 MB
    unsigned short* Epre = (unsigned short*)(wsf + 64 + NK + NTOK + 2097152);  // 4 MB
    unsigned short* Zpre = (unsigned short*)d_out;                // 16 MB scratch

    k_en    <<<NK / 4, 256, 0, stream>>>(E, en, acc, counter);
    k_castE <<<1024, 256, 0, stream>>>(E, Epre);
    k_castZ <<<2048, 256, 0, stream>>>(zg, Zpre);
    k_dist  <<<dim3(32, 256), 256, 0, stream>>>(Epre, Zpre, en, part2);
    k_refine<<<NTOK / 4, 256, 0, stream>>>(zg, E, part2, idxw, out);
    k_gather<<<512, 256, 0, stream>>>(E, zg, idxw, out, acc, counter);
}

// Round 6
// 318.877 us; speedup vs baseline: 6.5394x; 1.0914x over previous
//
#include <hip/hip_runtime.h>
#include <float.h>

// Problem constants
#define NBATCH 32
#define NCHAN  256
#define NHW    1024          // 32*32
#define NTOK   32768         // NBATCH * NHW
#define NK     8192          // codebook size
#define ND     256           // token dim
#define ZELEMS 8388608       // NBATCH*NCHAN*NHW
#define OUT_LOSS 8388608
#define OUT_IDX  8388611
#define MARGIN   1.2e-4f     // bf16 pre-screen err + fp32 quant tie window + slack

typedef short bf16x8  __attribute__((ext_vector_type(8)));
typedef float f32x4   __attribute__((ext_vector_type(4)));
typedef float f32x16  __attribute__((ext_vector_type(16)));

__device__ __forceinline__ void gl_lds16(const void* g, void* l) {
    __builtin_amdgcn_global_load_lds(
        (const __attribute__((address_space(1))) unsigned int*)g,
        (__attribute__((address_space(3))) unsigned int*)l, 16, 0, 0);
}

__device__ __forceinline__ unsigned short f2bf(float f) {   // RNE
    unsigned int u = __float_as_uint(f);
    u += 0x7FFFu + ((u >> 16) & 1u);
    return (unsigned short)(u >> 16);
}

__device__ __forceinline__ float embed8(float x, int code) {
    return __int_as_float((__float_as_int(x) & 0xFFFFFF00) | code);
}

// ws layout (floats):
//  [0] loss accumulator, [1] block counter (int)
//  [64 .. 64+8192)        en[k] = ||e_k||^2
//  [8256 .. +32768)       idxw (int) per token
//  [41024 .. +4194304)    part2: float2 [32768 tok][64 slots] (16 MB)
//  then                   Epre: bf16 E [64 tile][8 kc][4 plane][128 row][16B] (4 MB)
// Zpre (bf16 z, [256 mb][8 kc][4 plane][128 tok][16B], 16 MB) lives in
// d_out[0..16MB) until k_gather rewrites it.  plane = ks*2+lhi (K-subchunk).

// ---------------------------------------------------------------- cast E (+en)
__global__ __launch_bounds__(256) void k_castE(const float* __restrict__ E,
                                               unsigned short* __restrict__ Epre,
                                               float* __restrict__ en,
                                               float* __restrict__ acc,
                                               int* __restrict__ counter) {
    int g = blockIdx.x * 256 + threadIdx.x;      // 8192 codes * 32 chunks
    int code = g >> 5, c16 = g & 31;             // c16: 16B chunk = 8 channels
    int kc = c16 >> 2, ks = (c16 >> 1) & 1, lhi = c16 & 1;
    const float4* E4 = (const float4*)(E + code * ND + c16 * 8);
    float4 a = E4[0], b = E4[1];
    float s = a.x*a.x + a.y*a.y + a.z*a.z + a.w*a.w
            + b.x*b.x + b.y*b.y + b.z*b.z + b.w*b.w;
    #pragma unroll
    for (int off = 1; off < 32; off <<= 1) s += __shfl_xor(s, off, 64);
    if ((threadIdx.x & 31) == 0) en[code] = s;
    unsigned int u[4];
    u[0] = (unsigned int)f2bf(a.x) | ((unsigned int)f2bf(a.y) << 16);
    u[1] = (unsigned int)f2bf(a.z) | ((unsigned int)f2bf(a.w) << 16);
    u[2] = (unsigned int)f2bf(b.x) | ((unsigned int)f2bf(b.y) << 16);
    u[3] = (unsigned int)f2bf(b.z) | ((unsigned int)f2bf(b.w) << 16);
    *(uint4*)((char*)Epre + (size_t)(code >> 7) * 65536 + kc * 8192
              + (ks * 2 + lhi) * 2048 + (code & 127) * 16) =
        make_uint4(u[0], u[1], u[2], u[3]);
    if (blockIdx.x == 0 && threadIdx.x == 0) { acc[0] = 0.0f; counter[0] = 0; }
}

// ---------------------------------------------------------------- cast Z
__global__ __launch_bounds__(256) void k_castZ(const float* __restrict__ zg,
                                               unsigned short* __restrict__ Zpre) {
    __shared__ unsigned short buf[128][34];
    int bi = blockIdx.x;                  // 32 b * 8 kc * 8 hwt
    int b = bi >> 6, kc = (bi >> 3) & 7, hwt = bi & 7;
    int c0 = kc * 32, hw0 = hwt * 128;
    int t = threadIdx.x;
    #pragma unroll
    for (int r = 0; r < 4; ++r) {
        int idx = r * 256 + t;
        int c = idx >> 5, q = idx & 31;
        float4 v = *(const float4*)&zg[(b * 256 + c0 + c) * 1024 + hw0 + q * 4];
        buf[q * 4 + 0][c] = f2bf(v.x);
        buf[q * 4 + 1][c] = f2bf(v.y);
        buf[q * 4 + 2][c] = f2bf(v.z);
        buf[q * 4 + 3][c] = f2bf(v.w);
    }
    __syncthreads();
    int tok = t >> 1, ks = t & 1;
    char* base = (char*)Zpre + (size_t)((b * 8 + hwt) * 8 + kc) * 8192;
    #pragma unroll
    for (int lhi = 0; lhi < 2; ++lhi) {
        unsigned int u[4];
        #pragma unroll
        for (int k = 0; k < 4; ++k) {
            int cc = ks * 16 + lhi * 8 + 2 * k;
            u[k] = (unsigned int)buf[tok][cc] | ((unsigned int)buf[tok][cc + 1] << 16);
        }
        *(uint4*)(base + (ks * 2 + lhi) * 2048 + tok * 16) =
            make_uint4(u[0], u[1], u[2], u[3]);
    }
}

// ---------------------------------------------------------------- kernel 2
// MFMA pre-screen, D[code][token], 32x32x16 bf16. Block: 128 codes x 128
// tokens. E fragments loaded DIRECTLY from global (L2-resident), ping-pong
// prefetched; only Z goes through LDS (8KB/chunk, double-buffered).
// Per (token, 128-code slot): top-2 smallest s = ||e||^2 - 2 z.e, 7-bit
// local code index embedded in low mantissa bits.
__global__ __launch_bounds__(256, 3) void k_dist(const unsigned short* __restrict__ Epre,
                                                 const unsigned short* __restrict__ Zpre,
                                                 const float* __restrict__ en,
                                                 float2* __restrict__ part2) {
    __shared__ __align__(16) char Zs[16384];   // 2 x 8KB
    __shared__ float2 red[2][128];
    __shared__ float en_s[128];

    const int t    = threadIdx.x;
    const int kbb  = blockIdx.x;               // 0..63 (128 codes each)
    const int mb   = blockIdx.y;               // 0..255
    const int n0   = mb * 128;
    const int w    = t >> 6, lane = t & 63;
    const int l31  = lane & 31, lhi = lane >> 5;
    const int wm   = w >> 1, wn = w & 1;

    if (t < 128) en_s[t] = en[kbb * 128 + t];

    const char* Eb = (const char*)Epre + (size_t)kbb * 65536;
    const char* Zb = (const char*)Zpre + (size_t)mb * 65536;

    auto stage = [&](int kc, int buf) {
        char* db = Zs + buf * 8192;
        #pragma unroll
        for (int r = 0; r < 2; ++r) {
            int s = w * 2 + r;                 // wave-uniform segment
            gl_lds16(Zb + kc * 8192 + s * 1024 + lane * 16,
                     db + s * 1024 + lane * 16);
        }
    };

    bf16x8 ea[2][2][2];                        // [pp][i][ks]
    auto loadE = [&](int kc, int pp) {
        #pragma unroll
        for (int i = 0; i < 2; ++i)
            #pragma unroll
            for (int ks = 0; ks < 2; ++ks)
                ea[pp][i][ks] = *(const bf16x8*)(Eb + kc * 8192
                    + (ks * 2 + lhi) * 2048 + (wm * 64 + i * 32 + l31) * 16);
    };

    f32x16 acc[2][2];                          // [i][j]
    #pragma unroll
    for (int i = 0; i < 2; ++i)
        #pragma unroll
        for (int j = 0; j < 2; ++j) acc[i][j] = (f32x16)0.0f;

    loadE(0, 0);
    stage(0, 0);
    #pragma unroll
    for (int kc = 0; kc < 8; ++kc) {
        __syncthreads();                       // Z chunk kc ready
        if (kc < 7) {
            stage(kc + 1, (kc + 1) & 1);
            loadE(kc + 1, (kc + 1) & 1);
        }
        const char* zbuf = Zs + (kc & 1) * 8192;
        bf16x8 zb[2][2];                       // [j][ks]
        #pragma unroll
        for (int j = 0; j < 2; ++j)
            #pragma unroll
            for (int ks = 0; ks < 2; ++ks)
                zb[j][ks] = *(const bf16x8*)(zbuf + (ks * 2 + lhi) * 2048
                                             + (wn * 64 + j * 32 + l31) * 16);
        #pragma unroll
        for (int ks = 0; ks < 2; ++ks)
            #pragma unroll
            for (int i = 0; i < 2; ++i)
                #pragma unroll
                for (int j = 0; j < 2; ++j)
                    acc[i][j] = __builtin_amdgcn_mfma_f32_32x32x16_bf16(
                        ea[kc & 1][i][ks], zb[j][ks], acc[i][j], 0, 0, 0);
    }

    // ---- epilogue: per-token top-2 smallest s = en - 2*dot, index-embedded ----
    float v1[2] = { FLT_MAX, FLT_MAX }, v2[2] = { FLT_MAX, FLT_MAX };
    #pragma unroll
    for (int i = 0; i < 2; ++i) {
        const int cb = (wm << 6) | (i << 5) | (lhi << 2);
        #pragma unroll
        for (int rq = 0; rq < 4; ++rq) {
            f32x4 ev = *(const f32x4*)&en_s[cb + 8 * rq];
            #pragma unroll
            for (int rr = 0; rr < 4; ++rr) {
                const int r = rq * 4 + rr;
                const int code = cb + 8 * rq + rr;
                #pragma unroll
                for (int j = 0; j < 2; ++j) {
                    float s  = fmaf(-2.0f, acc[i][j][r], ev[rr]);
                    float se = embed8(s, code);
                    v2[j] = __builtin_amdgcn_fmed3f(se, v1[j], v2[j]);
                    v1[j] = fminf(v1[j], se);
                }
            }
        }
    }
    #pragma unroll
    for (int j = 0; j < 2; ++j) {              // merge lhi partner (xor 32)
        float b1 = __shfl_xor(v1[j], 32, 64);
        float b2 = __shfl_xor(v2[j], 32, 64);
        float hi = fmaxf(v1[j], b1);
        v1[j] = fminf(v1[j], b1);
        v2[j] = fminf(fminf(hi, v2[j]), b2);
    }
    if (lane < 32) {
        #pragma unroll
        for (int j = 0; j < 2; ++j)
            red[wm][wn * 64 + j * 32 + lane] = make_float2(v1[j], v2[j]);
    }
    __syncthreads();
    if (t < 128) {
        float2 A = red[0][t], B = red[1][t];
        float g1 = fminf(A.x, B.x);
        float g2 = fminf(fminf(fmaxf(A.x, B.x), A.y), B.y);
        part2[(size_t)(n0 + t) * 64 + kbb] = make_float2(g1, g2);
    }
}

// ---------------------------------------------------------------- kernel 3
// Refine: block stages z for 64 tokens into LDS (coalesced); per token-wave,
// mimic reference fp32 rounding:
//   d_q(k) = fl32( z2f - fl32(2*<z,e_k>_fp64) ), argmin, first-index ties.
__global__ __launch_bounds__(256) void k_refine(const float* __restrict__ zg,
                                                const float* __restrict__ E,
                                                const float2* __restrict__ part2,
                                                int* __restrict__ idxw,
                                                float* __restrict__ outF) {
    __shared__ float Zs[256 * 65];             // [c][tok] stride 65 (bank-clean)
    const int t = threadIdx.x;
    const int n0 = blockIdx.x * 64;
    const int b = n0 >> 10, hw0 = n0 & 1023;

    #pragma unroll
    for (int r = 0; r < 16; ++r) {
        int li = r * 256 + t;
        int c = li >> 4, q = li & 15;
        float4 v = *(const float4*)&zg[(b * 256 + c) * 1024 + hw0 + q * 4];
        Zs[c * 65 + q * 4 + 0] = v.x;
        Zs[c * 65 + q * 4 + 1] = v.y;
        Zs[c * 65 + q * 4 + 2] = v.z;
        Zs[c * 65 + q * 4 + 3] = v.w;
    }
    __syncthreads();

    const int w = t >> 6, l = t & 63;
    for (int it = 0; it < 16; ++it) {
        const int tokl = w * 16 + it;
        const int n = n0 + tokl;

        float zreg[4];
        #pragma unroll
        for (int j = 0; j < 4; ++j) zreg[j] = Zs[(64 * j + l) * 65 + tokl];

        double z2 = 0.0;
        #pragma unroll
        for (int j = 0; j < 4; ++j) z2 += (double)zreg[j] * (double)zreg[j];
        #pragma unroll
        for (int m = 1; m < 64; m <<= 1) z2 += __shfl_xor(z2, m, 64);
        const float z2f = (float)z2;

        float2 p = part2[(size_t)n * 64 + l];
        int code1 = (l << 7) | (__float_as_int(p.x) & 0x7F);
        int code2 = (l << 7) | (__float_as_int(p.y) & 0x7F);

        float vmin = p.x;
        #pragma unroll
        for (int m = 1; m < 64; m <<= 1) vmin = fminf(vmin, __shfl_xor(vmin, m, 64));
        const float thr = vmin + MARGIN;

        unsigned long long m1 = __ballot(p.x <= thr);
        unsigned long long m2 = __ballot(p.y <= thr);

        float bdq = FLT_MAX; int bidx = 0x7fffffff;
        #pragma unroll
        for (int pass = 0; pass < 2; ++pass) {
            unsigned long long mm = pass ? m2 : m1;
            int ibits = pass ? code2 : code1;
            while (mm) {
                int src = __ffsll(mm) - 1; mm &= mm - 1;
                int cidx = __shfl(ibits, src, 64);
                const float* erow = E + cidx * ND;
                double g = (double)zreg[0] * (double)erow[l]
                         + (double)zreg[1] * (double)erow[64 + l]
                         + (double)zreg[2] * (double)erow[128 + l]
                         + (double)zreg[3] * (double)erow[192 + l];
                #pragma unroll
                for (int mk = 1; mk < 64; mk <<= 1) g += __shfl_xor(g, mk, 64);
                float c  = (float)(2.0 * g);
                float dq = z2f - c;
                if (dq < bdq || (dq == bdq && cidx < bidx)) { bdq = dq; bidx = cidx; }
            }
        }
        if (l == 0) { idxw[n] = bidx; outF[OUT_IDX + n] = (float)bidx; }
    }
}

// ---------------------------------------------------------------- kernel 4
// Gather via LDS-staged E rows (coalesced 1KB row loads, XOR-swizzled),
// fused loss accumulation + last-block loss finalization.
__global__ __launch_bounds__(256) void k_gather(const float* __restrict__ E,
                                                const float* __restrict__ zg,
                                                const int* __restrict__ idxw,
                                                float* __restrict__ out,
                                                float* __restrict__ acc,
                                                int* __restrict__ counter) {
    __shared__ __align__(16) float Es[64 * 256];   // 64 rows x 1KB
    __shared__ int sidx[64];
    __shared__ float wred[4];
    const int t = threadIdx.x;
    const int b = blockIdx.x >> 4, ht = blockIdx.x & 15;

    if (t < 64) sidx[t] = idxw[b * 1024 + ht * 64 + t];
    __syncthreads();
    const float4* E4 = (const float4*)E;
    #pragma unroll
    for (int r = 0; r < 16; ++r) {
        int li = r * 256 + t;
        int row = li >> 6, slot = li & 63;
        float4 v = E4[(size_t)sidx[row] * 64 + slot];
        *(float4*)&Es[row * 256 + ((slot ^ (row & 15)) * 4)] = v;
    }
    __syncthreads();

    const int hw = t & 63, wv = t >> 6;
    float s = 0.0f;
    #pragma unroll 8
    for (int cc = 0; cc < 64; ++cc) {
        int c = wv * 64 + cc;
        float e = Es[hw * 256 + (((c >> 2) ^ (hw & 15)) * 4) + (c & 3)];
        size_t gi = (size_t)(b * 256 + c) * 1024 + ht * 64 + hw;
        float zv = zg[gi];
        out[gi] = e;
        float d = e - zv;
        s = fmaf(d, d, s);
    }
    #pragma unroll
    for (int off = 32; off > 0; off >>= 1) s += __shfl_down(s, off, 64);
    if ((t & 63) == 0) wred[wv] = s;
    __syncthreads();
    if (t == 0) {
        atomicAdd(acc, wred[0] + wred[1] + wred[2] + wred[3]);
        __threadfence();
        int old = atomicAdd(counter, 1);
        if (old == 511) {
            float total = atomicAdd(acc, 0.0f);   // RMW => device-coherent read
            float mse = total / 8388608.0f;
            out[OUT_LOSS + 0] = 1.25f * mse;
            out[OUT_LOSS + 1] = 0.25f * mse;
            out[OUT_LOSS + 2] = mse;
        }
    }
}

extern "C" void kernel_launch(void* const* d_in, const int* in_sizes, int n_in,
                              void* d_out, int out_size, void* d_ws, size_t ws_size,
                              hipStream_t stream) {
    const float* zg = (const float*)d_in[0];
    const float* E  = (const float*)d_in[1];
    float* out = (float*)d_out;
    float* wsf = (float*)d_ws;
    float*  acc     = wsf;
    int*    counter = (int*)(wsf + 1);
    float*  en      = wsf + 64;
    int*    idxw    = (int*)(wsf + 64 + NK);
    float2* part2   = (float2*)(wsf + 64 + NK + NTOK);            // 16 MB
    unsigned short* Epre = (unsigned short*)(wsf + 64 + NK + NTOK + 4194304);  // 4 MB
    unsigned short* Zpre = (unsigned short*)d_out;                // 16 MB scratch

    k_castE <<<1024, 256, 0, stream>>>(E, Epre, en, acc, counter);
    k_castZ <<<2048, 256, 0, stream>>>(zg, Zpre);
    k_dist  <<<dim3(64, 256), 256, 0, stream>>>(Epre, Zpre, en, part2);
    k_refine<<<NTOK / 64, 256, 0, stream>>>(zg, E, part2, idxw, out);
    k_gather<<<512, 256, 0, stream>>>(E, zg, idxw, out, acc, counter);
}

// Round 7
// 315.451 us; speedup vs baseline: 6.6104x; 1.0109x over previous
//
#include <hip/hip_runtime.h>
#include <float.h>

// Problem constants
#define NBATCH 32
#define NCHAN  256
#define NHW    1024          // 32*32
#define NTOK   32768         // NBATCH * NHW
#define NK     8192          // codebook size
#define ND     256           // token dim
#define ZELEMS 8388608       // NBATCH*NCHAN*NHW
#define OUT_LOSS 8388608
#define OUT_IDX  8388611
#define MARGIN   1.2e-4f     // bf16 pre-screen err + fp32 quant tie window + slack

typedef short bf16x8  __attribute__((ext_vector_type(8)));
typedef float f32x4   __attribute__((ext_vector_type(4)));
typedef float f32x16  __attribute__((ext_vector_type(16)));

__device__ __forceinline__ unsigned short f2bf(float f) {   // RNE
    unsigned int u = __float_as_uint(f);
    u += 0x7FFFu + ((u >> 16) & 1u);
    return (unsigned short)(u >> 16);
}

__device__ __forceinline__ float embed8(float x, int code) {
    return __int_as_float((__float_as_int(x) & 0xFFFFFF00) | code);
}

// ws layout (floats):
//  [0] loss accumulator, [1] block counter (int)
//  [64 .. 64+8192)        en[k] = ||e_k||^2
//  [8256 .. +32768)       idxw (int) per token
//  [41024 .. +4194304)    part2: float2 [32768 tok][64 slots] (16 MB)
//  then                   Epre: bf16 E [64 tile][8 kc][4 plane][128 row][16B] (4 MB)
// Zpre (bf16 z, [256 mb][8 kc][4 plane][128 tok][16B], 16 MB) lives in
// d_out[0..16MB) until k_gather rewrites it.  plane = ks*2+lhi (K-subchunk).

// ---------------------------------------------------------------- casts
// blocks [0,1024): E -> Epre (+ en, acc/counter init); [1024,3072): z -> Zpre
__global__ __launch_bounds__(256) void k_cast(const float* __restrict__ zg,
                                              const float* __restrict__ E,
                                              unsigned short* __restrict__ Epre,
                                              unsigned short* __restrict__ Zpre,
                                              float* __restrict__ en,
                                              float* __restrict__ acc,
                                              int* __restrict__ counter) {
    __shared__ unsigned short buf[128][34];
    const int t = threadIdx.x;
    if (blockIdx.x < 1024) {
        int g = blockIdx.x * 256 + t;                // 8192 codes * 32 chunks
        int code = g >> 5, c16 = g & 31;             // c16: 16B chunk = 8 channels
        int kc = c16 >> 2, ks = (c16 >> 1) & 1, lhi = c16 & 1;
        const float4* E4 = (const float4*)(E + code * ND + c16 * 8);
        float4 a = E4[0], b = E4[1];
        float s = a.x*a.x + a.y*a.y + a.z*a.z + a.w*a.w
                + b.x*b.x + b.y*b.y + b.z*b.z + b.w*b.w;
        #pragma unroll
        for (int off = 1; off < 32; off <<= 1) s += __shfl_xor(s, off, 64);
        if ((t & 31) == 0) en[code] = s;
        unsigned int u[4];
        u[0] = (unsigned int)f2bf(a.x) | ((unsigned int)f2bf(a.y) << 16);
        u[1] = (unsigned int)f2bf(a.z) | ((unsigned int)f2bf(a.w) << 16);
        u[2] = (unsigned int)f2bf(b.x) | ((unsigned int)f2bf(b.y) << 16);
        u[3] = (unsigned int)f2bf(b.z) | ((unsigned int)f2bf(b.w) << 16);
        *(uint4*)((char*)Epre + (size_t)(code >> 7) * 65536 + kc * 8192
                  + (ks * 2 + lhi) * 2048 + (code & 127) * 16) =
            make_uint4(u[0], u[1], u[2], u[3]);
        if (blockIdx.x == 0 && t == 0) { acc[0] = 0.0f; counter[0] = 0; }
    } else {
        int bi = blockIdx.x - 1024;           // 32 b * 8 kc * 8 hwt
        int b = bi >> 6, kc = (bi >> 3) & 7, hwt = bi & 7;
        int c0 = kc * 32, hw0 = hwt * 128;
        #pragma unroll
        for (int r = 0; r < 4; ++r) {
            int idx = r * 256 + t;
            int c = idx >> 5, q = idx & 31;
            float4 v = *(const float4*)&zg[(b * 256 + c0 + c) * 1024 + hw0 + q * 4];
            buf[q * 4 + 0][c] = f2bf(v.x);
            buf[q * 4 + 1][c] = f2bf(v.y);
            buf[q * 4 + 2][c] = f2bf(v.z);
            buf[q * 4 + 3][c] = f2bf(v.w);
        }
        __syncthreads();
        int tok = t >> 1, ks = t & 1;
        char* base = (char*)Zpre + (size_t)((b * 8 + hwt) * 8 + kc) * 8192;
        #pragma unroll
        for (int lhi = 0; lhi < 2; ++lhi) {
            unsigned int u[4];
            #pragma unroll
            for (int k = 0; k < 4; ++k) {
                int cc = ks * 16 + lhi * 8 + 2 * k;
                u[k] = (unsigned int)buf[tok][cc] | ((unsigned int)buf[tok][cc + 1] << 16);
            }
            *(uint4*)(base + (ks * 2 + lhi) * 2048 + tok * 16) =
                make_uint4(u[0], u[1], u[2], u[3]);
        }
    }
}

// ---------------------------------------------------------------- kernel 2
// MFMA pre-screen, D[code][token], 32x32x16 bf16. Block: 128 codes x 128
// tokens. BOTH operands loaded directly from global (L2-resident) into
// VGPRs, explicit ping-pong, ZERO barriers in the K-loop -> compiler
// schedules with fine-grained vmcnt instead of per-chunk vmcnt(0) drains.
// Per (token, 128-code slot): top-2 smallest s = ||e||^2 - 2 z.e, 7-bit
// local code index embedded in low mantissa bits.
__global__ __launch_bounds__(256, 3) void k_dist(const unsigned short* __restrict__ Epre,
                                                 const unsigned short* __restrict__ Zpre,
                                                 const float* __restrict__ en,
                                                 float2* __restrict__ part2) {
    __shared__ float2 red[2][128];
    __shared__ float en_s[128];

    const int t    = threadIdx.x;
    const int kbb  = blockIdx.x;               // 0..63 (128 codes each)
    const int mb   = blockIdx.y;               // 0..255
    const int n0   = mb * 128;
    const int w    = t >> 6, lane = t & 63;
    const int l31  = lane & 31, lhi = lane >> 5;
    const int wm   = w >> 1, wn = w & 1;

    if (t < 128) en_s[t] = en[kbb * 128 + t];
    __syncthreads();                           // en_s ready for epilogue

    const char* Ep = (const char*)Epre + (size_t)kbb * 65536
                   + lhi * 2048 + (wm * 64 + l31) * 16;
    const char* Zp = (const char*)Zpre + (size_t)mb * 65536
                   + lhi * 2048 + (wn * 64 + l31) * 16;

    bf16x8 ea[2][2][2], zb[2][2][2];           // [pp][i/j][ks]
    auto loadE = [&](int kc, int pp) {
        const char* p = Ep + kc * 8192;
        #pragma unroll
        for (int i = 0; i < 2; ++i)
            #pragma unroll
            for (int ks = 0; ks < 2; ++ks)
                ea[pp][i][ks] = *(const bf16x8*)(p + ks * 4096 + i * 512);
    };
    auto loadZ = [&](int kc, int pp) {
        const char* p = Zp + kc * 8192;
        #pragma unroll
        for (int j = 0; j < 2; ++j)
            #pragma unroll
            for (int ks = 0; ks < 2; ++ks)
                zb[pp][j][ks] = *(const bf16x8*)(p + ks * 4096 + j * 512);
    };

    f32x16 acc[2][2];                          // [i][j]
    #pragma unroll
    for (int i = 0; i < 2; ++i)
        #pragma unroll
        for (int j = 0; j < 2; ++j) acc[i][j] = (f32x16)0.0f;

    loadE(0, 0);
    loadZ(0, 0);
    #pragma unroll
    for (int kc = 0; kc < 8; ++kc) {
        const int pp = kc & 1;
        if (kc < 7) { loadE(kc + 1, pp ^ 1); loadZ(kc + 1, pp ^ 1); }
        #pragma unroll
        for (int ks = 0; ks < 2; ++ks)
            #pragma unroll
            for (int i = 0; i < 2; ++i)
                #pragma unroll
                for (int j = 0; j < 2; ++j)
                    acc[i][j] = __builtin_amdgcn_mfma_f32_32x32x16_bf16(
                        ea[pp][i][ks], zb[pp][j][ks], acc[i][j], 0, 0, 0);
    }

    // ---- epilogue: per-token top-2 smallest s = en - 2*dot, index-embedded ----
    float v1[2] = { FLT_MAX, FLT_MAX }, v2[2] = { FLT_MAX, FLT_MAX };
    #pragma unroll
    for (int i = 0; i < 2; ++i) {
        const int cb = (wm << 6) | (i << 5) | (lhi << 2);
        #pragma unroll
        for (int rq = 0; rq < 4; ++rq) {
            f32x4 ev = *(const f32x4*)&en_s[cb + 8 * rq];
            #pragma unroll
            for (int rr = 0; rr < 4; ++rr) {
                const int r = rq * 4 + rr;
                const int code = cb + 8 * rq + rr;
                #pragma unroll
                for (int j = 0; j < 2; ++j) {
                    float s  = fmaf(-2.0f, acc[i][j][r], ev[rr]);
                    float se = embed8(s, code);
                    v2[j] = __builtin_amdgcn_fmed3f(se, v1[j], v2[j]);
                    v1[j] = fminf(v1[j], se);
                }
            }
        }
    }
    #pragma unroll
    for (int j = 0; j < 2; ++j) {              // merge lhi partner (xor 32)
        float b1 = __shfl_xor(v1[j], 32, 64);
        float b2 = __shfl_xor(v2[j], 32, 64);
        float hi = fmaxf(v1[j], b1);
        v1[j] = fminf(v1[j], b1);
        v2[j] = fminf(fminf(hi, v2[j]), b2);
    }
    if (lane < 32) {
        #pragma unroll
        for (int j = 0; j < 2; ++j)
            red[wm][wn * 64 + j * 32 + lane] = make_float2(v1[j], v2[j]);
    }
    __syncthreads();
    if (t < 128) {
        float2 A = red[0][t], B = red[1][t];
        float g1 = fminf(A.x, B.x);
        float g2 = fminf(fminf(fmaxf(A.x, B.x), A.y), B.y);
        part2[(size_t)(n0 + t) * 64 + kbb] = make_float2(g1, g2);
    }
}

// ---------------------------------------------------------------- kernel 3
// Refine: block stages z for 64 tokens into LDS (coalesced); per token-wave,
// mimic reference fp32 rounding:
//   d_q(k) = fl32( z2f - fl32(2*<z,e_k>_fp64) ), argmin, first-index ties.
__global__ __launch_bounds__(256) void k_refine(const float* __restrict__ zg,
                                                const float* __restrict__ E,
                                                const float2* __restrict__ part2,
                                                int* __restrict__ idxw,
                                                float* __restrict__ outF) {
    __shared__ float Zs[256 * 65];             // [c][tok] stride 65 (bank-clean)
    const int t = threadIdx.x;
    const int n0 = blockIdx.x * 64;
    const int b = n0 >> 10, hw0 = n0 & 1023;

    #pragma unroll
    for (int r = 0; r < 16; ++r) {
        int li = r * 256 + t;
        int c = li >> 4, q = li & 15;
        float4 v = *(const float4*)&zg[(b * 256 + c) * 1024 + hw0 + q * 4];
        Zs[c * 65 + q * 4 + 0] = v.x;
        Zs[c * 65 + q * 4 + 1] = v.y;
        Zs[c * 65 + q * 4 + 2] = v.z;
        Zs[c * 65 + q * 4 + 3] = v.w;
    }
    __syncthreads();

    const int w = t >> 6, l = t & 63;
    for (int it = 0; it < 16; ++it) {
        const int tokl = w * 16 + it;
        const int n = n0 + tokl;

        float zreg[4];
        #pragma unroll
        for (int j = 0; j < 4; ++j) zreg[j] = Zs[(64 * j + l) * 65 + tokl];

        double z2 = 0.0;
        #pragma unroll
        for (int j = 0; j < 4; ++j) z2 += (double)zreg[j] * (double)zreg[j];
        #pragma unroll
        for (int m = 1; m < 64; m <<= 1) z2 += __shfl_xor(z2, m, 64);
        const float z2f = (float)z2;

        float2 p = part2[(size_t)n * 64 + l];
        int code1 = (l << 7) | (__float_as_int(p.x) & 0x7F);
        int code2 = (l << 7) | (__float_as_int(p.y) & 0x7F);

        float vmin = p.x;
        #pragma unroll
        for (int m = 1; m < 64; m <<= 1) vmin = fminf(vmin, __shfl_xor(vmin, m, 64));
        const float thr = vmin + MARGIN;

        unsigned long long m1 = __ballot(p.x <= thr);
        unsigned long long m2 = __ballot(p.y <= thr);

        float bdq = FLT_MAX; int bidx = 0x7fffffff;
        #pragma unroll
        for (int pass = 0; pass < 2; ++pass) {
            unsigned long long mm = pass ? m2 : m1;
            int ibits = pass ? code2 : code1;
            while (mm) {
                int src = __ffsll(mm) - 1; mm &= mm - 1;
                int cidx = __shfl(ibits, src, 64);
                const float* erow = E + cidx * ND;
                double g = (double)zreg[0] * (double)erow[l]
                         + (double)zreg[1] * (double)erow[64 + l]
                         + (double)zreg[2] * (double)erow[128 + l]
                         + (double)zreg[3] * (double)erow[192 + l];
                #pragma unroll
                for (int mk = 1; mk < 64; mk <<= 1) g += __shfl_xor(g, mk, 64);
                float c  = (float)(2.0 * g);
                float dq = z2f - c;
                if (dq < bdq || (dq == bdq && cidx < bidx)) { bdq = dq; bidx = cidx; }
            }
        }
        if (l == 0) { idxw[n] = bidx; outF[OUT_IDX + n] = (float)bidx; }
    }
}

// ---------------------------------------------------------------- kernel 4
// Gather via LDS-staged E rows (coalesced 1KB row loads, XOR-swizzled),
// fused loss accumulation + last-block loss finalization.
__global__ __launch_bounds__(256) void k_gather(const float* __restrict__ E,
                                                const float* __restrict__ zg,
                                                const int* __restrict__ idxw,
                                                float* __restrict__ out,
                                                float* __restrict__ acc,
                                                int* __restrict__ counter) {
    __shared__ __align__(16) float Es[64 * 256];   // 64 rows x 1KB
    __shared__ int sidx[64];
    __shared__ float wred[4];
    const int t = threadIdx.x;
    const int b = blockIdx.x >> 4, ht = blockIdx.x & 15;

    if (t < 64) sidx[t] = idxw[b * 1024 + ht * 64 + t];
    __syncthreads();
    const float4* E4 = (const float4*)E;
    #pragma unroll
    for (int r = 0; r < 16; ++r) {
        int li = r * 256 + t;
        int row = li >> 6, slot = li & 63;
        float4 v = E4[(size_t)sidx[row] * 64 + slot];
        *(float4*)&Es[row * 256 + ((slot ^ (row & 15)) * 4)] = v;
    }
    __syncthreads();

    const int hw = t & 63, wv = t >> 6;
    float s = 0.0f;
    #pragma unroll 8
    for (int cc = 0; cc < 64; ++cc) {
        int c = wv * 64 + cc;
        float e = Es[hw * 256 + (((c >> 2) ^ (hw & 15)) * 4) + (c & 3)];
        size_t gi = (size_t)(b * 256 + c) * 1024 + ht * 64 + hw;
        float zv = zg[gi];
        out[gi] = e;
        float d = e - zv;
        s = fmaf(d, d, s);
    }
    #pragma unroll
    for (int off = 32; off > 0; off >>= 1) s += __shfl_down(s, off, 64);
    if ((t & 63) == 0) wred[wv] = s;
    __syncthreads();
    if (t == 0) {
        atomicAdd(acc, wred[0] + wred[1] + wred[2] + wred[3]);
        __threadfence();
        int old = atomicAdd(counter, 1);
        if (old == 511) {
            float total = atomicAdd(acc, 0.0f);   // RMW => device-coherent read
            float mse = total / 8388608.0f;
            out[OUT_LOSS + 0] = 1.25f * mse;
            out[OUT_LOSS + 1] = 0.25f * mse;
            out[OUT_LOSS + 2] = mse;
        }
    }
}

extern "C" void kernel_launch(void* const* d_in, const int* in_sizes, int n_in,
                              void* d_out, int out_size, void* d_ws, size_t ws_size,
                              hipStream_t stream) {
    const float* zg = (const float*)d_in[0];
    const float* E  = (const float*)d_in[1];
    float* out = (float*)d_out;
    float* wsf = (float*)d_ws;
    float*  acc     = wsf;
    int*    counter = (int*)(wsf + 1);
    float*  en      = wsf + 64;
    int*    idxw    = (int*)(wsf + 64 + NK);
    float2* part2   = (float2*)(wsf + 64 + NK + NTOK);            // 16 MB
    unsigned short* Epre = (unsigned short*)(wsf + 64 + NK + NTOK + 4194304);  // 4 MB
    unsigned short* Zpre = (unsigned short*)d_out;                // 16 MB scratch

    k_cast  <<<3072, 256, 0, stream>>>(zg, E, Epre, Zpre, en, acc, counter);
    k_dist  <<<dim3(64, 256), 256, 0, stream>>>(Epre, Zpre, en, part2);
    k_refine<<<NTOK / 64, 256, 0, stream>>>(zg, E, part2, idxw, out);
    k_gather<<<512, 256, 0, stream>>>(E, zg, idxw, out, acc, counter);
}